// Round 13
// baseline (173.805 us; speedup 1.0000x reference)
//
#include <hip/hip_runtime.h>
#include <math.h>

#define NN 1024
#define BB 2
#define D 64
#define NHEAD 4
#define LOG2E 1.4426950408889634f
#define MST 65

template <int CTRL>
__device__ __forceinline__ float dpp_mov(float x) {
    int xi = __builtin_bit_cast(int, x);
    int r = __builtin_amdgcn_update_dpp(0, xi, CTRL, 0xF, 0xF, true);
    return __builtin_bit_cast(float, r);
}
template <int CTRL>
__device__ __forceinline__ unsigned dpp_movi(unsigned x) {
    int r = __builtin_amdgcn_update_dpp(0, (int)x, CTRL, 0xF, 0xF, true);
    return (unsigned)r;
}

// 16-lane row sum; valid in lane 15 of each row of 16.
__device__ __forceinline__ float dpp_rowsum16(float t) {
    t += dpp_mov<0x111>(t);
    t += dpp_mov<0x112>(t);
    t += dpp_mov<0x114>(t);
    t += dpp_mov<0x118>(t);
    return t;
}

// --- Kernel 1: merged {adjacency mask GEMM} + {layer-1 dual GEMM} --------
// (round-8 verbatim, verified)
__global__ __launch_bounds__(256) void k_mask_gemm(
    const float* __restrict__ emb, unsigned char* __restrict__ mask,
    const float* __restrict__ A, const float* __restrict__ Wl,
    const float* __restrict__ Wr, const float* __restrict__ att,
    float* __restrict__ xl, float* __restrict__ xr, float* __restrict__ alE)
{
    __shared__ float SH[64 * MST * 2];
    int tid = threadIdx.x;
    if (blockIdx.x < 256) {
        float* As = SH;
        float* Bs = SH + 64 * MST;
        int ib = (blockIdx.x & 15) << 6;
        int jb = (blockIdx.x >> 4) << 6;

        #pragma unroll
        for (int r = 0; r < 4; ++r) {
            int q = tid + (r << 8);
            int row = q >> 4, c4 = (q & 15) << 2;
            float4 a = *(const float4*)&emb[(ib + row) * D + c4];
            float4 b = *(const float4*)&emb[(jb + row) * D + c4];
            As[row * MST + c4 + 0] = a.x; As[row * MST + c4 + 1] = a.y;
            As[row * MST + c4 + 2] = a.z; As[row * MST + c4 + 3] = a.w;
            Bs[row * MST + c4 + 0] = b.x; Bs[row * MST + c4 + 1] = b.y;
            Bs[row * MST + c4 + 2] = b.z; Bs[row * MST + c4 + 3] = b.w;
        }
        __syncthreads();

        int i0 = (tid >> 4) << 2;
        int j0 = (tid & 15) << 2;
        float acc[4][4] = {};
        #pragma unroll 8
        for (int k = 0; k < 64; ++k) {
            float a0 = As[(i0 + 0) * MST + k];
            float a1 = As[(i0 + 1) * MST + k];
            float a2 = As[(i0 + 2) * MST + k];
            float a3 = As[(i0 + 3) * MST + k];
            float b0 = Bs[(j0 + 0) * MST + k];
            float b1 = Bs[(j0 + 1) * MST + k];
            float b2 = Bs[(j0 + 2) * MST + k];
            float b3 = Bs[(j0 + 3) * MST + k];
            acc[0][0] = fmaf(a0, b0, acc[0][0]); acc[0][1] = fmaf(a0, b1, acc[0][1]);
            acc[0][2] = fmaf(a0, b2, acc[0][2]); acc[0][3] = fmaf(a0, b3, acc[0][3]);
            acc[1][0] = fmaf(a1, b0, acc[1][0]); acc[1][1] = fmaf(a1, b1, acc[1][1]);
            acc[1][2] = fmaf(a1, b2, acc[1][2]); acc[1][3] = fmaf(a1, b3, acc[1][3]);
            acc[2][0] = fmaf(a2, b0, acc[2][0]); acc[2][1] = fmaf(a2, b1, acc[2][1]);
            acc[2][2] = fmaf(a2, b2, acc[2][2]); acc[2][3] = fmaf(a2, b3, acc[2][3]);
            acc[3][0] = fmaf(a3, b0, acc[3][0]); acc[3][1] = fmaf(a3, b1, acc[3][1]);
            acc[3][2] = fmaf(a3, b2, acc[3][2]); acc[3][3] = fmaf(a3, b3, acc[3][3]);
        }
        #pragma unroll
        for (int r = 0; r < 4; ++r) {
            int gi = ib + i0 + r;
            uchar4 m;
            m.x = (acc[r][0] != 0.f || gi == jb + j0 + 0) ? 1 : 0;
            m.y = (acc[r][1] != 0.f || gi == jb + j0 + 1) ? 1 : 0;
            m.z = (acc[r][2] != 0.f || gi == jb + j0 + 2) ? 1 : 0;
            m.w = (acc[r][3] != 0.f || gi == jb + j0 + 3) ? 1 : 0;
            *(uchar4*)&mask[gi * NN + jb + j0] = m;
        }
    } else {
        float* wl = SH;
        float* wr = SH + 4096;
        for (int t = tid; t < 4096; t += 256) { wl[t] = Wl[t]; wr[t] = Wr[t]; }
        __syncthreads();
        int r = (blockIdx.x - 256) * 4 + (tid >> 6);
        int c = tid & 63;
        float av = att[c];
        const float* arow = A + r * 64;
        float accl = 0.f, accr = 0.f;
        #pragma unroll
        for (int p = 0; p < 64; ++p) {
            float a = arow[p];
            accl = fmaf(a, wl[p * 64 + c], accl);
            accr = fmaf(a, wr[p * 64 + c], accr);
        }
        // permuted xl store: logical col c = h*16 + c4*4 + r  ->  c4*16 + h*4 + r
        int cp = (((c >> 2) & 3) << 4) | ((c >> 4) << 2) | (c & 3);
        xl[r * 64 + cp] = accl;
        xr[r * 64 + c] = accr;
        float t = dpp_rowsum16(accl * av);
        if ((c & 15) == 15) alE[(r << 2) | (c >> 4)] = 0.6f * LOG2E * t;
    }
}

// --- Kernel 2: fused flash GATv2, head-per-lane, dense tiles, 8 ROWS -----
// Ledger: instr count (r8) / async LDS (r6) / flight depth (r12) all
// neutral; dense tiles (r11) +7us; ROW AMORTIZATION (r4->r5, 4x rows)
// 1.75x. Only amortization + transaction density ever paid -> push rows
// to 8 per block. VGPR ~380 > 256 -> __launch_bounds__(256,1) (cap 512,
// 1 wave/SIMD, 1 block/CU, grid 256 = exactly 256 CUs, tail-free). A
// single wave64 can saturate a SIMD-32 issue port; per-iter issue ~940cy
// also doubles staging flight. Per-CU xv/LDS traffic per pair HALVES.
// Math per pair and j-order identical to r12 -> absmax exactly 3.814697e-06.
// Per-row state = SEPARATE NAMED 16-float arrays (SROA rule, rounds 2-3).
// FUSEG (row-local attn1->gemm2, r10-verified): SHW unions with XS.
template <bool RELU, bool FUSEG>
__global__ __launch_bounds__(256, 1) void k_attn(
    const float* __restrict__ xlp, const float* __restrict__ xr,
    const float* __restrict__ att, const float* __restrict__ alE,
    const float* __restrict__ bias, const unsigned char* __restrict__ mask,
    float* __restrict__ out,
    const float* __restrict__ Wl2, const float* __restrict__ Wr2,
    const float* __restrict__ att2,
    float* __restrict__ xl2, float* __restrict__ xr2, float* __restrict__ alE2)
{
    __shared__ __align__(16) float XS[8192];    // XBUF[4][2][1024] then SHW
    __shared__ float Opart[8][4][4][64];        // [ii][wave][jlgrp][p] 32KB
    __shared__ float Lpart[8][4][4][NHEAD];
    __shared__ float RES[8][64];                // FUSEG: block's 8 out rows

    int tid = threadIdx.x;
    int wave = tid >> 6, lane = tid & 63;
    int h = lane & 3, jl = lane >> 2;
    int b = blockIdx.x >> 7;
    int i0 = (blockIdx.x & 127) << 3;

    const float* xlb = xlp + (b << 16);

    // natural head-h slices: at[p] = att[h][p], xr?f[p] = xr[row][h*16+p]
    float at[16];
    float xr0f[16], xr1f[16], xr2f[16], xr3f[16];
    float xr4f[16], xr5f[16], xr6f[16], xr7f[16];
    {
        const float* ap = att + (h << 4);
        const float* r0 = xr + (((b << 10) + i0) << 6) + (h << 4);
        #pragma unroll
        for (int c = 0; c < 4; ++c) {
            *(float4*)&at[c << 2]   = *(const float4*)(ap + (c << 2));
            *(float4*)&xr0f[c << 2] = *(const float4*)(r0 + (c << 2));
            *(float4*)&xr1f[c << 2] = *(const float4*)(r0 + 64 + (c << 2));
            *(float4*)&xr2f[c << 2] = *(const float4*)(r0 + 128 + (c << 2));
            *(float4*)&xr3f[c << 2] = *(const float4*)(r0 + 192 + (c << 2));
            *(float4*)&xr4f[c << 2] = *(const float4*)(r0 + 256 + (c << 2));
            *(float4*)&xr5f[c << 2] = *(const float4*)(r0 + 320 + (c << 2));
            *(float4*)&xr6f[c << 2] = *(const float4*)(r0 + 384 + (c << 2));
            *(float4*)&xr7f[c << 2] = *(const float4*)(r0 + 448 + (c << 2));
        }
        #pragma unroll
        for (int p = 0; p < 16; ++p) at[p] *= 0.4f * LOG2E;
    }
    // arE per row, fully in-lane (same chain groups + tree -> bit-identical)
    float ar0, ar1, ar2, ar3, ar4, ar5, ar6, ar7;
    {
        float s0[4], s1[4], s2[4], s3[4], s4[4], s5[4], s6[4], s7[4];
        #pragma unroll
        for (int c = 0; c < 4; ++c) {
            float t0 = 0.f, t1 = 0.f, t2 = 0.f, t3 = 0.f;
            float t4 = 0.f, t5 = 0.f, t6 = 0.f, t7 = 0.f;
            #pragma unroll
            for (int r = 0; r < 4; ++r) {
                int p = (c << 2) + r;
                float a = at[p];
                t0 = fmaf(a, xr0f[p], t0);
                t1 = fmaf(a, xr1f[p], t1);
                t2 = fmaf(a, xr2f[p], t2);
                t3 = fmaf(a, xr3f[p], t3);
                t4 = fmaf(a, xr4f[p], t4);
                t5 = fmaf(a, xr5f[p], t5);
                t6 = fmaf(a, xr6f[p], t6);
                t7 = fmaf(a, xr7f[p], t7);
            }
            s0[c] = t0; s1[c] = t1; s2[c] = t2; s3[c] = t3;
            s4[c] = t4; s5[c] = t5; s6[c] = t6; s7[c] = t7;
        }
        ar0 = 1.5f * ((s0[0] + s0[1]) + (s0[2] + s0[3]));
        ar1 = 1.5f * ((s1[0] + s1[1]) + (s1[2] + s1[3]));
        ar2 = 1.5f * ((s2[0] + s2[1]) + (s2[2] + s2[3]));
        ar3 = 1.5f * ((s3[0] + s3[1]) + (s3[2] + s3[3]));
        ar4 = 1.5f * ((s4[0] + s4[1]) + (s4[2] + s4[3]));
        ar5 = 1.5f * ((s5[0] + s5[1]) + (s5[2] + s5[3]));
        ar6 = 1.5f * ((s6[0] + s6[1]) + (s6[2] + s6[3]));
        ar7 = 1.5f * ((s7[0] + s7[1]) + (s7[2] + s7[3]));
    }

    // mask bits for j = wave*256 + s*16 + jl, rows i0..i0+7
    unsigned mb0, mb1, mb2, mb3, mb4, mb5, mb6, mb7;
    {
        const unsigned char* mp = mask + i0 * NN + (wave << 8) + jl;
        int hh = h << 6;
        unsigned nv[8];
        #pragma unroll
        for (int rw = 0; rw < 8; ++rw) {
            nv[rw] = (unsigned)mp[hh] | ((unsigned)mp[hh + 16] << 1)
                   | ((unsigned)mp[hh + 32] << 2) | ((unsigned)mp[hh + 48] << 3);
            mp += NN;
        }
        unsigned sh = h << 2;
        unsigned v0 = nv[0] << sh, v1 = nv[1] << sh, v2 = nv[2] << sh, v3 = nv[3] << sh;
        unsigned v4 = nv[4] << sh, v5 = nv[5] << sh, v6 = nv[6] << sh, v7 = nv[7] << sh;
        v0 |= dpp_movi<0xB1>(v0); v0 |= dpp_movi<0x4E>(v0);
        v1 |= dpp_movi<0xB1>(v1); v1 |= dpp_movi<0x4E>(v1);
        v2 |= dpp_movi<0xB1>(v2); v2 |= dpp_movi<0x4E>(v2);
        v3 |= dpp_movi<0xB1>(v3); v3 |= dpp_movi<0x4E>(v3);
        v4 |= dpp_movi<0xB1>(v4); v4 |= dpp_movi<0x4E>(v4);
        v5 |= dpp_movi<0xB1>(v5); v5 |= dpp_movi<0x4E>(v5);
        v6 |= dpp_movi<0xB1>(v6); v6 |= dpp_movi<0x4E>(v6);
        v7 |= dpp_movi<0xB1>(v7); v7 |= dpp_movi<0x4E>(v7);
        mb0 = v0; mb1 = v1; mb2 = v2; mb3 = v3;
        mb4 = v4; mb5 = v5; mb6 = v6; mb7 = v7;
    }

    float O0[16], O1[16], O2[16], O3[16], O4[16], O5[16], O6[16], O7[16];
    float lq0 = 0.f, lq1 = 0.f, lq2 = 0.f, lq3 = 0.f;
    float lq4 = 0.f, lq5 = 0.f, lq6 = 0.f, lq7 = 0.f;
    #pragma unroll
    for (int p = 0; p < 16; ++p) {
        O0[p] = 0.f; O1[p] = 0.f; O2[p] = 0.f; O3[p] = 0.f;
        O4[p] = 0.f; O5[p] = 0.f; O6[p] = 0.f; O7[p] = 0.f;
    }

    // --- dense-tile staging setup (r11 addresses) ---
    const float* tb = xlb + (wave << 14);     // wave's 256 rows (16 tiles)
    float* XB = XS + (wave << 11);            // wave-private [2][1024]
    int l4 = lane << 2;
    int rowoff = (lane >> 4) << 6;
    int sb = (lane & 15) ^ (lane >> 4);
    int A0 = rowoff + (sb << 2);
    int A1 = rowoff + ((sb ^ 4) << 2);
    int qx = (jl >> 2) & 1;
    int rb = (jl << 6) + ((h ^ (jl & 3)) << 2);
    const float* alp = alE + (b << 12) + (wave << 10) + lane;

    // --- 2-deep prologue: tile0->A, tile1->B, write A->buf0, tile2->A ---
    float4 gA0, gA1, gA2, gA3, gB0, gB1, gB2, gB3;
    {
        const float* p = tb + l4;
        gA0 = *(const float4*)p;         gA1 = *(const float4*)(p + 256);
        gA2 = *(const float4*)(p + 512); gA3 = *(const float4*)(p + 768);
        p = tb + 1024 + l4;
        gB0 = *(const float4*)p;         gB1 = *(const float4*)(p + 256);
        gB2 = *(const float4*)(p + 512); gB3 = *(const float4*)(p + 768);
        *(float4*)&XB[A0] = gA0;         *(float4*)&XB[256 + A1] = gA1;
        *(float4*)&XB[512 + A0] = gA2;   *(float4*)&XB[768 + A1] = gA3;
        p = tb + 2048 + l4;
        gA0 = *(const float4*)p;         gA1 = *(const float4*)(p + 256);
        gA2 = *(const float4*)(p + 512); gA3 = *(const float4*)(p + 768);
    }

    #pragma unroll 2
    for (int s = 0; s < 16; ++s) {
        if ((s & 1) == 0) {
            if (s < 15) {
                float* w = XB + (((s + 1) & 1) << 10);
                *(float4*)&w[A0] = gB0;         *(float4*)&w[256 + A1] = gB1;
                *(float4*)&w[512 + A0] = gB2;   *(float4*)&w[768 + A1] = gB3;
            }
            if (s < 13) {
                const float* p = tb + ((s + 3) << 10) + l4;
                gB0 = *(const float4*)p;         gB1 = *(const float4*)(p + 256);
                gB2 = *(const float4*)(p + 512); gB3 = *(const float4*)(p + 768);
            }
        } else {
            if (s < 15) {
                float* w = XB + (((s + 1) & 1) << 10);
                *(float4*)&w[A0] = gA0;         *(float4*)&w[256 + A1] = gA1;
                *(float4*)&w[512 + A0] = gA2;   *(float4*)&w[768 + A1] = gA3;
            }
            if (s < 13) {
                const float* p = tb + ((s + 3) << 10) + l4;
                gA0 = *(const float4*)p;         gA1 = *(const float4*)(p + 256);
                gA2 = *(const float4*)(p + 512); gA3 = *(const float4*)(p + 768);
            }
        }

        const float* XBr = XB + ((s & 1) << 10);
        float xv[16];
        *(float4*)&xv[0]  = *(const float4*)&XBr[rb + (((0 ^ qx)) << 4)];
        *(float4*)&xv[4]  = *(const float4*)&XBr[rb + (((1 ^ qx)) << 4)];
        *(float4*)&xv[8]  = *(const float4*)&XBr[rb + (((2 ^ qx)) << 4)];
        *(float4*)&xv[12] = *(const float4*)&XBr[rb + (((3 ^ qx)) << 4)];
        float alr = alp[s << 6];
        bool m0 = (mb0 >> s) & 1, m1 = (mb1 >> s) & 1;
        bool m2 = (mb2 >> s) & 1, m3 = (mb3 >> s) & 1;
        bool m4 = (mb4 >> s) & 1, m5 = (mb5 >> s) & 1;
        bool m6 = (mb6 >> s) & 1, m7 = (mb7 >> s) & 1;

        float s0[4], s1[4], s2[4], s3[4], s4[4], s5[4], s6[4], s7[4];
        #pragma unroll
        for (int c = 0; c < 4; ++c) {
            float t0 = 0.f, t1 = 0.f, t2 = 0.f, t3 = 0.f;
            float t4 = 0.f, t5 = 0.f, t6 = 0.f, t7 = 0.f;
            #pragma unroll
            for (int r = 0; r < 4; ++r) {
                int p = (c << 2) + r;
                float a = at[p], xvv = xv[p];
                t0 = fmaf(a, __builtin_fabsf(xr0f[p] + xvv), t0);
                t1 = fmaf(a, __builtin_fabsf(xr1f[p] + xvv), t1);
                t2 = fmaf(a, __builtin_fabsf(xr2f[p] + xvv), t2);
                t3 = fmaf(a, __builtin_fabsf(xr3f[p] + xvv), t3);
                t4 = fmaf(a, __builtin_fabsf(xr4f[p] + xvv), t4);
                t5 = fmaf(a, __builtin_fabsf(xr5f[p] + xvv), t5);
                t6 = fmaf(a, __builtin_fabsf(xr6f[p] + xvv), t6);
                t7 = fmaf(a, __builtin_fabsf(xr7f[p] + xvv), t7);
            }
            s0[c] = t0; s1[c] = t1; s2[c] = t2; s3[c] = t3;
            s4[c] = t4; s5[c] = t5; s6[c] = t6; s7[c] = t7;
        }
        float e0 = ((s0[0] + s0[1]) + (s0[2] + s0[3])) + (ar0 + alr);
        float e1 = ((s1[0] + s1[1]) + (s1[2] + s1[3])) + (ar1 + alr);
        float e2 = ((s2[0] + s2[1]) + (s2[2] + s2[3])) + (ar2 + alr);
        float e3 = ((s3[0] + s3[1]) + (s3[2] + s3[3])) + (ar3 + alr);
        float e4 = ((s4[0] + s4[1]) + (s4[2] + s4[3])) + (ar4 + alr);
        float e5 = ((s5[0] + s5[1]) + (s5[2] + s5[3])) + (ar5 + alr);
        float e6 = ((s6[0] + s6[1]) + (s6[2] + s6[3])) + (ar6 + alr);
        float e7 = ((s7[0] + s7[1]) + (s7[2] + s7[3])) + (ar7 + alr);
        float pe0 = m0 ? __builtin_amdgcn_exp2f(e0) : 0.f;
        float pe1 = m1 ? __builtin_amdgcn_exp2f(e1) : 0.f;
        float pe2 = m2 ? __builtin_amdgcn_exp2f(e2) : 0.f;
        float pe3 = m3 ? __builtin_amdgcn_exp2f(e3) : 0.f;
        float pe4 = m4 ? __builtin_amdgcn_exp2f(e4) : 0.f;
        float pe5 = m5 ? __builtin_amdgcn_exp2f(e5) : 0.f;
        float pe6 = m6 ? __builtin_amdgcn_exp2f(e6) : 0.f;
        float pe7 = m7 ? __builtin_amdgcn_exp2f(e7) : 0.f;
        lq0 += pe0; lq1 += pe1; lq2 += pe2; lq3 += pe3;
        lq4 += pe4; lq5 += pe5; lq6 += pe6; lq7 += pe7;
        #pragma unroll
        for (int p = 0; p < 16; ++p) {
            float xvv = xv[p];
            O0[p] = fmaf(pe0, xvv, O0[p]);
            O1[p] = fmaf(pe1, xvv, O1[p]);
            O2[p] = fmaf(pe2, xvv, O2[p]);
            O3[p] = fmaf(pe3, xvv, O3[p]);
            O4[p] = fmaf(pe4, xvv, O4[p]);
            O5[p] = fmaf(pe5, xvv, O5[p]);
            O6[p] = fmaf(pe6, xvv, O6[p]);
            O7[p] = fmaf(pe7, xvv, O7[p]);
        }
    }

    if constexpr (FUSEG) {
        __syncthreads();               // all waves done reading XS tiles
        for (int t = tid; t < 4096; t += 256) { XS[t] = Wl2[t]; XS[4096 + t] = Wr2[t]; }
    }

    // reduce over the 4 jl's within each 16-lane DPP row (stride-4 lanes)
    #pragma unroll
    for (int p = 0; p < 16; ++p) {
        O0[p] += dpp_mov<0x114>(O0[p]);  O0[p] += dpp_mov<0x118>(O0[p]);
        O1[p] += dpp_mov<0x114>(O1[p]);  O1[p] += dpp_mov<0x118>(O1[p]);
        O2[p] += dpp_mov<0x114>(O2[p]);  O2[p] += dpp_mov<0x118>(O2[p]);
        O3[p] += dpp_mov<0x114>(O3[p]);  O3[p] += dpp_mov<0x118>(O3[p]);
        O4[p] += dpp_mov<0x114>(O4[p]);  O4[p] += dpp_mov<0x118>(O4[p]);
        O5[p] += dpp_mov<0x114>(O5[p]);  O5[p] += dpp_mov<0x118>(O5[p]);
        O6[p] += dpp_mov<0x114>(O6[p]);  O6[p] += dpp_mov<0x118>(O6[p]);
        O7[p] += dpp_mov<0x114>(O7[p]);  O7[p] += dpp_mov<0x118>(O7[p]);
    }
    lq0 += dpp_mov<0x114>(lq0);  lq0 += dpp_mov<0x118>(lq0);
    lq1 += dpp_mov<0x114>(lq1);  lq1 += dpp_mov<0x118>(lq1);
    lq2 += dpp_mov<0x114>(lq2);  lq2 += dpp_mov<0x118>(lq2);
    lq3 += dpp_mov<0x114>(lq3);  lq3 += dpp_mov<0x118>(lq3);
    lq4 += dpp_mov<0x114>(lq4);  lq4 += dpp_mov<0x118>(lq4);
    lq5 += dpp_mov<0x114>(lq5);  lq5 += dpp_mov<0x118>(lq5);
    lq6 += dpp_mov<0x114>(lq6);  lq6 += dpp_mov<0x118>(lq6);
    lq7 += dpp_mov<0x114>(lq7);  lq7 += dpp_mov<0x118>(lq7);

    if ((lane & 15) >= 12) {             // lanes 12..15 of each DPP row
        int k = lane >> 4;               // jl-group
        #pragma unroll
        for (int c = 0; c < 4; ++c) {
            *(float4*)&Opart[0][wave][k][(h << 4) + (c << 2)] = *(const float4*)&O0[c << 2];
            *(float4*)&Opart[1][wave][k][(h << 4) + (c << 2)] = *(const float4*)&O1[c << 2];
            *(float4*)&Opart[2][wave][k][(h << 4) + (c << 2)] = *(const float4*)&O2[c << 2];
            *(float4*)&Opart[3][wave][k][(h << 4) + (c << 2)] = *(const float4*)&O3[c << 2];
            *(float4*)&Opart[4][wave][k][(h << 4) + (c << 2)] = *(const float4*)&O4[c << 2];
            *(float4*)&Opart[5][wave][k][(h << 4) + (c << 2)] = *(const float4*)&O5[c << 2];
            *(float4*)&Opart[6][wave][k][(h << 4) + (c << 2)] = *(const float4*)&O6[c << 2];
            *(float4*)&Opart[7][wave][k][(h << 4) + (c << 2)] = *(const float4*)&O7[c << 2];
        }
        Lpart[0][wave][k][h] = lq0;
        Lpart[1][wave][k][h] = lq1;
        Lpart[2][wave][k][h] = lq2;
        Lpart[3][wave][k][h] = lq3;
        Lpart[4][wave][k][h] = lq4;
        Lpart[5][wave][k][h] = lq5;
        Lpart[6][wave][k][h] = lq6;
        Lpart[7][wave][k][h] = lq7;
    }
    __syncthreads();                     // covers Opart/Lpart (+ SHW stage)

    {
        int c = tid & 63;
        #pragma unroll
        for (int pass = 0; pass < 2; ++pass) {
            int ii = (tid >> 6) + (pass << 2);
            float o = 0.f, l = 0.f;
            #pragma unroll
            for (int w = 0; w < 4; ++w)
                #pragma unroll
                for (int k = 0; k < 4; ++k) {
                    o += Opart[ii][w][k][c];
                    l += Lpart[ii][w][k][c >> 4];
                }
            float res = o / l + bias[c];
            if (RELU) res = fmaxf(res, 0.f);
            if constexpr (FUSEG) {
                RES[ii][c] = res;        // hbuf never touches global
            } else {
                out[((b << 10) + i0 + ii) * D + c] = res;
            }
        }
    }

    if constexpr (FUSEG) {
        __syncthreads();
        // next-layer dual GEMM on this block's 8 rows (row-local dep)
        int c = tid & 63;
        float av = att2[c];
        int cp = (((c >> 2) & 3) << 4) | ((c >> 4) << 2) | (c & 3);
        #pragma unroll
        for (int pass = 0; pass < 2; ++pass) {
            int ii = (tid >> 6) + (pass << 2);
            int rr = (blockIdx.x << 3) + ii;
            const float* arow = &RES[ii][0];
            float accl = 0.f, accr = 0.f;
            #pragma unroll
            for (int p = 0; p < 64; ++p) {
                float a = arow[p];                    // LDS broadcast read
                accl = fmaf(a, XS[p * 64 + c], accl);
                accr = fmaf(a, XS[4096 + p * 64 + c], accr);
            }
            xl2[rr * 64 + cp] = accl;
            xr2[rr * 64 + c] = accr;
            float t = dpp_rowsum16(accl * av);
            if ((c & 15) == 15) alE2[(rr << 2) | (c >> 4)] = 0.6f * LOG2E * t;
        }
    }
}

extern "C" void kernel_launch(void* const* d_in, const int* in_sizes, int n_in,
                              void* d_out, int out_size, void* d_ws, size_t ws_size,
                              hipStream_t stream) {
    const float* x    = (const float*)d_in[0];
    const float* emb  = (const float*)d_in[1];
    const float* Wl1  = (const float*)d_in[2];
    const float* Wr1  = (const float*)d_in[3];
    const float* att1 = (const float*)d_in[4];
    const float* b1   = (const float*)d_in[5];
    const float* Wl2  = (const float*)d_in[6];
    const float* Wr2  = (const float*)d_in[7];
    const float* att2 = (const float*)d_in[8];
    const float* b2   = (const float*)d_in[9];
    float* out = (float*)d_out;

    unsigned char* mask = (unsigned char*)d_ws;                 // 1MB
    float* xl   = (float*)(mask + NN * NN);                     // 512KB (permuted)
    float* xr   = xl + BB * NN * D;                             // 512KB
    float* xl2  = xr + BB * NN * D;                             // 512KB (permuted)
    float* alE  = xl2 + BB * NN * D;                            // 32KB
    float* xr2  = alE + BB * NN * NHEAD;                        // 512KB
    float* alE2 = xr2 + BB * NN * D;                            // 32KB

    k_mask_gemm<<<256 + BB * NN / 4, 256, 0, stream>>>(emb, mask, x, Wl1, Wr1, att1, xl, xr, alE);

    // attn layer 1 (relu) + fused layer-2 dual GEMM (row-local dependency)
    k_attn<true, true><<<BB * NN / 8, 256, 0, stream>>>(
        xl, xr, att1, alE, b1, mask, xl2 /*unused out*/,
        Wl2, Wr2, att2, xl2, xr2, alE2);

    // attn layer 2 -> final output
    k_attn<false, false><<<BB * NN / 8, 256, 0, stream>>>(
        xl2, xr2, att2, alE2, b2, mask, out,
        Wl2, Wr2, att2, xl2, xr2, alE2 /*unused*/);
}

// Round 14
// 122.926 us; speedup vs baseline: 1.4139x; 1.4139x over previous
//
#include <hip/hip_runtime.h>
#include <math.h>

#define NN 1024
#define BB 2
#define D 64
#define NHEAD 4
#define LOG2E 1.4426950408889634f
#define MST 65

template <int CTRL>
__device__ __forceinline__ float dpp_mov(float x) {
    int xi = __builtin_bit_cast(int, x);
    int r = __builtin_amdgcn_update_dpp(0, xi, CTRL, 0xF, 0xF, true);
    return __builtin_bit_cast(float, r);
}
template <int CTRL>
__device__ __forceinline__ unsigned dpp_movi(unsigned x) {
    int r = __builtin_amdgcn_update_dpp(0, (int)x, CTRL, 0xF, 0xF, true);
    return (unsigned)r;
}

// 16-lane row sum; valid in lane 15 of each row of 16.
__device__ __forceinline__ float dpp_rowsum16(float t) {
    t += dpp_mov<0x111>(t);
    t += dpp_mov<0x112>(t);
    t += dpp_mov<0x114>(t);
    t += dpp_mov<0x118>(t);
    return t;
}

// --- Kernel 1: merged {adjacency mask GEMM} + {layer-1 dual GEMM} --------
// (round-8 verbatim, verified)
__global__ __launch_bounds__(256) void k_mask_gemm(
    const float* __restrict__ emb, unsigned char* __restrict__ mask,
    const float* __restrict__ A, const float* __restrict__ Wl,
    const float* __restrict__ Wr, const float* __restrict__ att,
    float* __restrict__ xl, float* __restrict__ xr, float* __restrict__ alE)
{
    __shared__ float SH[64 * MST * 2];
    int tid = threadIdx.x;
    if (blockIdx.x < 256) {
        float* As = SH;
        float* Bs = SH + 64 * MST;
        int ib = (blockIdx.x & 15) << 6;
        int jb = (blockIdx.x >> 4) << 6;

        #pragma unroll
        for (int r = 0; r < 4; ++r) {
            int q = tid + (r << 8);
            int row = q >> 4, c4 = (q & 15) << 2;
            float4 a = *(const float4*)&emb[(ib + row) * D + c4];
            float4 b = *(const float4*)&emb[(jb + row) * D + c4];
            As[row * MST + c4 + 0] = a.x; As[row * MST + c4 + 1] = a.y;
            As[row * MST + c4 + 2] = a.z; As[row * MST + c4 + 3] = a.w;
            Bs[row * MST + c4 + 0] = b.x; Bs[row * MST + c4 + 1] = b.y;
            Bs[row * MST + c4 + 2] = b.z; Bs[row * MST + c4 + 3] = b.w;
        }
        __syncthreads();

        int i0 = (tid >> 4) << 2;
        int j0 = (tid & 15) << 2;
        float acc[4][4] = {};
        #pragma unroll 8
        for (int k = 0; k < 64; ++k) {
            float a0 = As[(i0 + 0) * MST + k];
            float a1 = As[(i0 + 1) * MST + k];
            float a2 = As[(i0 + 2) * MST + k];
            float a3 = As[(i0 + 3) * MST + k];
            float b0 = Bs[(j0 + 0) * MST + k];
            float b1 = Bs[(j0 + 1) * MST + k];
            float b2 = Bs[(j0 + 2) * MST + k];
            float b3 = Bs[(j0 + 3) * MST + k];
            acc[0][0] = fmaf(a0, b0, acc[0][0]); acc[0][1] = fmaf(a0, b1, acc[0][1]);
            acc[0][2] = fmaf(a0, b2, acc[0][2]); acc[0][3] = fmaf(a0, b3, acc[0][3]);
            acc[1][0] = fmaf(a1, b0, acc[1][0]); acc[1][1] = fmaf(a1, b1, acc[1][1]);
            acc[1][2] = fmaf(a1, b2, acc[1][2]); acc[1][3] = fmaf(a1, b3, acc[1][3]);
            acc[2][0] = fmaf(a2, b0, acc[2][0]); acc[2][1] = fmaf(a2, b1, acc[2][1]);
            acc[2][2] = fmaf(a2, b2, acc[2][2]); acc[2][3] = fmaf(a2, b3, acc[2][3]);
            acc[3][0] = fmaf(a3, b0, acc[3][0]); acc[3][1] = fmaf(a3, b1, acc[3][1]);
            acc[3][2] = fmaf(a3, b2, acc[3][2]); acc[3][3] = fmaf(a3, b3, acc[3][3]);
        }
        #pragma unroll
        for (int r = 0; r < 4; ++r) {
            int gi = ib + i0 + r;
            uchar4 m;
            m.x = (acc[r][0] != 0.f || gi == jb + j0 + 0) ? 1 : 0;
            m.y = (acc[r][1] != 0.f || gi == jb + j0 + 1) ? 1 : 0;
            m.z = (acc[r][2] != 0.f || gi == jb + j0 + 2) ? 1 : 0;
            m.w = (acc[r][3] != 0.f || gi == jb + j0 + 3) ? 1 : 0;
            *(uchar4*)&mask[gi * NN + jb + j0] = m;
        }
    } else {
        float* wl = SH;
        float* wr = SH + 4096;
        for (int t = tid; t < 4096; t += 256) { wl[t] = Wl[t]; wr[t] = Wr[t]; }
        __syncthreads();
        int r = (blockIdx.x - 256) * 4 + (tid >> 6);
        int c = tid & 63;
        float av = att[c];
        const float* arow = A + r * 64;
        float accl = 0.f, accr = 0.f;
        #pragma unroll
        for (int p = 0; p < 64; ++p) {
            float a = arow[p];
            accl = fmaf(a, wl[p * 64 + c], accl);
            accr = fmaf(a, wr[p * 64 + c], accr);
        }
        // permuted xl store: logical col c = h*16 + c4*4 + r  ->  c4*16 + h*4 + r
        int cp = (((c >> 2) & 3) << 4) | ((c >> 4) << 2) | (c & 3);
        xl[r * 64 + cp] = accl;
        xr[r * 64 + c] = accr;
        float t = dpp_rowsum16(accl * av);
        if ((c & 15) == 15) alE[(r << 2) | (c >> 4)] = 0.6f * LOG2E * t;
    }
}

// --- Kernel 2: fused flash GATv2, head-per-lane, dense tiles, 2-DEEP -----
// ROUND-12 VERBATIM (verified best: 121.1us total). Round-13 lesson:
// gfx950 non-MFMA code caps at 256 architectural VGPRs (upper half of the
// unified file is AGPR-only) -> 4 rows/block (~206 live) is the maximum
// spill-free geometry; 8 rows spilled (WRITE_SIZE 11.8MB, occupancy <10%,
// 174us total). Dense-tile staging (r11, +7us) is the only confirmed
// memory-path lever; instr count / async staging / flight depth all
// neutral. Per-row state = SEPARATE NAMED 16-float arrays (SROA rule).
// FUSEG (row-local attn1->gemm2, r10-verified): SHW unions with XS.
template <bool RELU, bool FUSEG>
__global__ __launch_bounds__(256, 2) void k_attn(
    const float* __restrict__ xlp, const float* __restrict__ xr,
    const float* __restrict__ att, const float* __restrict__ alE,
    const float* __restrict__ bias, const unsigned char* __restrict__ mask,
    float* __restrict__ out,
    const float* __restrict__ Wl2, const float* __restrict__ Wr2,
    const float* __restrict__ att2,
    float* __restrict__ xl2, float* __restrict__ xr2, float* __restrict__ alE2)
{
    __shared__ __align__(16) float XS[8192];    // XBUF[4][2][1024] then SHW
    __shared__ float Opart[4][4][4][64];        // [ii][wave][jlgrp][p]
    __shared__ float Lpart[4][4][4][NHEAD];
    __shared__ float RES[4][64];                // FUSEG: block's 4 out rows

    int tid = threadIdx.x;
    int wave = tid >> 6, lane = tid & 63;
    int h = lane & 3, jl = lane >> 2;
    int b = blockIdx.x >> 8;
    int i0 = (blockIdx.x & 255) << 2;

    const float* xlb = xlp + (b << 16);

    // natural head-h slices: at[p] = att[h][p], xr?f[p] = xr[row][h*16+p]
    float at[16], xr0f[16], xr1f[16], xr2f[16], xr3f[16];
    {
        const float* ap = att + (h << 4);
        const float* r0 = xr + (((b << 10) + i0) << 6) + (h << 4);
        const float* r1 = r0 + 64;
        const float* r2 = r0 + 128;
        const float* r3 = r0 + 192;
        #pragma unroll
        for (int c = 0; c < 4; ++c) {
            *(float4*)&at[c << 2]   = *(const float4*)(ap + (c << 2));
            *(float4*)&xr0f[c << 2] = *(const float4*)(r0 + (c << 2));
            *(float4*)&xr1f[c << 2] = *(const float4*)(r1 + (c << 2));
            *(float4*)&xr2f[c << 2] = *(const float4*)(r2 + (c << 2));
            *(float4*)&xr3f[c << 2] = *(const float4*)(r3 + (c << 2));
        }
        #pragma unroll
        for (int p = 0; p < 16; ++p) at[p] *= 0.4f * LOG2E;
    }
    // arE per row, fully in-lane (unchanged)
    float ar0, ar1, ar2, ar3;
    {
        float s0[4], s1[4], s2[4], s3[4];
        #pragma unroll
        for (int c = 0; c < 4; ++c) {
            float t0 = 0.f, t1 = 0.f, t2 = 0.f, t3 = 0.f;
            #pragma unroll
            for (int r = 0; r < 4; ++r) {
                int p = (c << 2) + r;
                float a = at[p];
                t0 = fmaf(a, xr0f[p], t0);
                t1 = fmaf(a, xr1f[p], t1);
                t2 = fmaf(a, xr2f[p], t2);
                t3 = fmaf(a, xr3f[p], t3);
            }
            s0[c] = t0; s1[c] = t1; s2[c] = t2; s3[c] = t3;
        }
        ar0 = 1.5f * ((s0[0] + s0[1]) + (s0[2] + s0[3]));
        ar1 = 1.5f * ((s1[0] + s1[1]) + (s1[2] + s1[3]));
        ar2 = 1.5f * ((s2[0] + s2[1]) + (s2[2] + s2[3]));
        ar3 = 1.5f * ((s3[0] + s3[1]) + (s3[2] + s3[3]));
    }

    // mask bits for j = wave*256 + s*16 + jl (r11 verbatim)
    unsigned mb0, mb1, mb2, mb3;
    {
        const unsigned char* mp = mask + i0 * NN + (wave << 8) + jl;
        int hh = h << 6;                 // (4h)*16 bytes
        unsigned n0 = (unsigned)mp[hh] | ((unsigned)mp[hh + 16] << 1)
                    | ((unsigned)mp[hh + 32] << 2) | ((unsigned)mp[hh + 48] << 3);
        mp += NN;
        unsigned n1 = (unsigned)mp[hh] | ((unsigned)mp[hh + 16] << 1)
                    | ((unsigned)mp[hh + 32] << 2) | ((unsigned)mp[hh + 48] << 3);
        mp += NN;
        unsigned n2 = (unsigned)mp[hh] | ((unsigned)mp[hh + 16] << 1)
                    | ((unsigned)mp[hh + 32] << 2) | ((unsigned)mp[hh + 48] << 3);
        mp += NN;
        unsigned n3 = (unsigned)mp[hh] | ((unsigned)mp[hh + 16] << 1)
                    | ((unsigned)mp[hh + 32] << 2) | ((unsigned)mp[hh + 48] << 3);
        unsigned v0 = n0 << (h << 2), v1 = n1 << (h << 2);
        unsigned v2 = n2 << (h << 2), v3 = n3 << (h << 2);
        v0 |= dpp_movi<0xB1>(v0); v0 |= dpp_movi<0x4E>(v0);
        v1 |= dpp_movi<0xB1>(v1); v1 |= dpp_movi<0x4E>(v1);
        v2 |= dpp_movi<0xB1>(v2); v2 |= dpp_movi<0x4E>(v2);
        v3 |= dpp_movi<0xB1>(v3); v3 |= dpp_movi<0x4E>(v3);
        mb0 = v0; mb1 = v1; mb2 = v2; mb3 = v3;
    }

    float O0[16], O1[16], O2[16], O3[16];
    float lq0 = 0.f, lq1 = 0.f, lq2 = 0.f, lq3 = 0.f;
    #pragma unroll
    for (int p = 0; p < 16; ++p) { O0[p] = 0.f; O1[p] = 0.f; O2[p] = 0.f; O3[p] = 0.f; }

    // --- dense-tile staging setup (addresses r11 verbatim) ---
    const float* tb = xlb + (wave << 14);     // wave's 256 rows (16 tiles)
    float* XB = XS + (wave << 11);            // wave-private [2][1024]
    int l4 = lane << 2;
    int rowoff = (lane >> 4) << 6;
    int sb = (lane & 15) ^ (lane >> 4);
    int A0 = rowoff + (sb << 2);
    int A1 = rowoff + ((sb ^ 4) << 2);
    int qx = (jl >> 2) & 1;
    int rb = (jl << 6) + ((h ^ (jl & 3)) << 2);
    const float* alp = alE + (b << 12) + (wave << 10) + lane;

    // --- 2-deep prologue: tile0->A, tile1->B, write A->buf0, tile2->A ---
    float4 gA0, gA1, gA2, gA3, gB0, gB1, gB2, gB3;
    {
        const float* p = tb + l4;
        gA0 = *(const float4*)p;         gA1 = *(const float4*)(p + 256);
        gA2 = *(const float4*)(p + 512); gA3 = *(const float4*)(p + 768);
        p = tb + 1024 + l4;
        gB0 = *(const float4*)p;         gB1 = *(const float4*)(p + 256);
        gB2 = *(const float4*)(p + 512); gB3 = *(const float4*)(p + 768);
        *(float4*)&XB[A0] = gA0;         *(float4*)&XB[256 + A1] = gA1;
        *(float4*)&XB[512 + A0] = gA2;   *(float4*)&XB[768 + A1] = gA3;
        p = tb + 2048 + l4;
        gA0 = *(const float4*)p;         gA1 = *(const float4*)(p + 256);
        gA2 = *(const float4*)(p + 512); gA3 = *(const float4*)(p + 768);
    }

    #pragma unroll 2
    for (int s = 0; s < 16; ++s) {
        // even s: write B (tile s+1) -> buf((s+1)&1), reload B with s+3.
        // odd  s: same with A.  Flight for a tile = 2 full iterations.
        if ((s & 1) == 0) {
            if (s < 15) {
                float* w = XB + (((s + 1) & 1) << 10);
                *(float4*)&w[A0] = gB0;         *(float4*)&w[256 + A1] = gB1;
                *(float4*)&w[512 + A0] = gB2;   *(float4*)&w[768 + A1] = gB3;
            }
            if (s < 13) {
                const float* p = tb + ((s + 3) << 10) + l4;
                gB0 = *(const float4*)p;         gB1 = *(const float4*)(p + 256);
                gB2 = *(const float4*)(p + 512); gB3 = *(const float4*)(p + 768);
            }
        } else {
            if (s < 15) {
                float* w = XB + (((s + 1) & 1) << 10);
                *(float4*)&w[A0] = gA0;         *(float4*)&w[256 + A1] = gA1;
                *(float4*)&w[512 + A0] = gA2;   *(float4*)&w[768 + A1] = gA3;
            }
            if (s < 13) {
                const float* p = tb + ((s + 3) << 10) + l4;
                gA0 = *(const float4*)p;         gA1 = *(const float4*)(p + 256);
                gA2 = *(const float4*)(p + 512); gA3 = *(const float4*)(p + 768);
            }
        }

        const float* XBr = XB + ((s & 1) << 10);
        float xv[16];
        *(float4*)&xv[0]  = *(const float4*)&XBr[rb + (((0 ^ qx)) << 4)];
        *(float4*)&xv[4]  = *(const float4*)&XBr[rb + (((1 ^ qx)) << 4)];
        *(float4*)&xv[8]  = *(const float4*)&XBr[rb + (((2 ^ qx)) << 4)];
        *(float4*)&xv[12] = *(const float4*)&XBr[rb + (((3 ^ qx)) << 4)];
        float alr = alp[s << 6];
        bool m0 = (mb0 >> s) & 1, m1 = (mb1 >> s) & 1;
        bool m2 = (mb2 >> s) & 1, m3 = (mb3 >> s) & 1;

        float s0[4], s1[4], s2[4], s3[4];
        #pragma unroll
        for (int c = 0; c < 4; ++c) {
            float t0 = 0.f, t1 = 0.f, t2 = 0.f, t3 = 0.f;
            #pragma unroll
            for (int r = 0; r < 4; ++r) {
                int p = (c << 2) + r;
                float a = at[p], xvv = xv[p];
                t0 = fmaf(a, __builtin_fabsf(xr0f[p] + xvv), t0);
                t1 = fmaf(a, __builtin_fabsf(xr1f[p] + xvv), t1);
                t2 = fmaf(a, __builtin_fabsf(xr2f[p] + xvv), t2);
                t3 = fmaf(a, __builtin_fabsf(xr3f[p] + xvv), t3);
            }
            s0[c] = t0; s1[c] = t1; s2[c] = t2; s3[c] = t3;
        }
        float e0 = ((s0[0] + s0[1]) + (s0[2] + s0[3])) + (ar0 + alr);
        float e1 = ((s1[0] + s1[1]) + (s1[2] + s1[3])) + (ar1 + alr);
        float e2 = ((s2[0] + s2[1]) + (s2[2] + s2[3])) + (ar2 + alr);
        float e3 = ((s3[0] + s3[1]) + (s3[2] + s3[3])) + (ar3 + alr);
        float pe0 = m0 ? __builtin_amdgcn_exp2f(e0) : 0.f;
        float pe1 = m1 ? __builtin_amdgcn_exp2f(e1) : 0.f;
        float pe2 = m2 ? __builtin_amdgcn_exp2f(e2) : 0.f;
        float pe3 = m3 ? __builtin_amdgcn_exp2f(e3) : 0.f;
        lq0 += pe0; lq1 += pe1; lq2 += pe2; lq3 += pe3;
        #pragma unroll
        for (int p = 0; p < 16; ++p) {
            float xvv = xv[p];
            O0[p] = fmaf(pe0, xvv, O0[p]);
            O1[p] = fmaf(pe1, xvv, O1[p]);
            O2[p] = fmaf(pe2, xvv, O2[p]);
            O3[p] = fmaf(pe3, xvv, O3[p]);
        }
    }

    if constexpr (FUSEG) {
        __syncthreads();               // all waves done reading XS tiles
        for (int t = tid; t < 4096; t += 256) { XS[t] = Wl2[t]; XS[4096 + t] = Wr2[t]; }
    }

    // reduce over the 4 jl's within each 16-lane DPP row (stride-4 lanes)
    #pragma unroll
    for (int p = 0; p < 16; ++p) {
        O0[p] += dpp_mov<0x114>(O0[p]);  O0[p] += dpp_mov<0x118>(O0[p]);
        O1[p] += dpp_mov<0x114>(O1[p]);  O1[p] += dpp_mov<0x118>(O1[p]);
        O2[p] += dpp_mov<0x114>(O2[p]);  O2[p] += dpp_mov<0x118>(O2[p]);
        O3[p] += dpp_mov<0x114>(O3[p]);  O3[p] += dpp_mov<0x118>(O3[p]);
    }
    lq0 += dpp_mov<0x114>(lq0);  lq0 += dpp_mov<0x118>(lq0);
    lq1 += dpp_mov<0x114>(lq1);  lq1 += dpp_mov<0x118>(lq1);
    lq2 += dpp_mov<0x114>(lq2);  lq2 += dpp_mov<0x118>(lq2);
    lq3 += dpp_mov<0x114>(lq3);  lq3 += dpp_mov<0x118>(lq3);

    if ((lane & 15) >= 12) {             // lanes 12..15 of each DPP row
        int k = lane >> 4;               // jl-group
        #pragma unroll
        for (int c = 0; c < 4; ++c) {
            *(float4*)&Opart[0][wave][k][(h << 4) + (c << 2)] = *(const float4*)&O0[c << 2];
            *(float4*)&Opart[1][wave][k][(h << 4) + (c << 2)] = *(const float4*)&O1[c << 2];
            *(float4*)&Opart[2][wave][k][(h << 4) + (c << 2)] = *(const float4*)&O2[c << 2];
            *(float4*)&Opart[3][wave][k][(h << 4) + (c << 2)] = *(const float4*)&O3[c << 2];
        }
        Lpart[0][wave][k][h] = lq0;
        Lpart[1][wave][k][h] = lq1;
        Lpart[2][wave][k][h] = lq2;
        Lpart[3][wave][k][h] = lq3;
    }
    __syncthreads();                     // covers Opart/Lpart (+ SHW stage)

    {
        int ii = tid >> 6, c = tid & 63;
        float o = 0.f, l = 0.f;
        #pragma unroll
        for (int w = 0; w < 4; ++w)
            #pragma unroll
            for (int k = 0; k < 4; ++k) {
                o += Opart[ii][w][k][c];
                l += Lpart[ii][w][k][c >> 4];
            }
        float res = o / l + bias[c];
        if (RELU) res = fmaxf(res, 0.f);
        if constexpr (FUSEG) {
            RES[ii][c] = res;            // hbuf never touches global
        } else {
            out[((b << 10) + i0 + ii) * D + c] = res;
        }
    }

    if constexpr (FUSEG) {
        __syncthreads();
        // next-layer dual GEMM on this block's 4 rows (row-local dep)
        int ii = tid >> 6, c = tid & 63;
        int rr = (blockIdx.x << 2) + ii;
        float av = att2[c];
        const float* arow = &RES[ii][0];
        float accl = 0.f, accr = 0.f;
        #pragma unroll
        for (int p = 0; p < 64; ++p) {
            float a = arow[p];                    // LDS broadcast read
            accl = fmaf(a, XS[p * 64 + c], accl);
            accr = fmaf(a, XS[4096 + p * 64 + c], accr);
        }
        int cp = (((c >> 2) & 3) << 4) | ((c >> 4) << 2) | (c & 3);
        xl2[rr * 64 + cp] = accl;
        xr2[rr * 64 + c] = accr;
        float t = dpp_rowsum16(accl * av);
        if ((c & 15) == 15) alE2[(rr << 2) | (c >> 4)] = 0.6f * LOG2E * t;
    }
}

extern "C" void kernel_launch(void* const* d_in, const int* in_sizes, int n_in,
                              void* d_out, int out_size, void* d_ws, size_t ws_size,
                              hipStream_t stream) {
    const float* x    = (const float*)d_in[0];
    const float* emb  = (const float*)d_in[1];
    const float* Wl1  = (const float*)d_in[2];
    const float* Wr1  = (const float*)d_in[3];
    const float* att1 = (const float*)d_in[4];
    const float* b1   = (const float*)d_in[5];
    const float* Wl2  = (const float*)d_in[6];
    const float* Wr2  = (const float*)d_in[7];
    const float* att2 = (const float*)d_in[8];
    const float* b2   = (const float*)d_in[9];
    float* out = (float*)d_out;

    unsigned char* mask = (unsigned char*)d_ws;                 // 1MB
    float* xl   = (float*)(mask + NN * NN);                     // 512KB (permuted)
    float* xr   = xl + BB * NN * D;                             // 512KB
    float* xl2  = xr + BB * NN * D;                             // 512KB (permuted)
    float* alE  = xl2 + BB * NN * D;                            // 32KB
    float* xr2  = alE + BB * NN * NHEAD;                        // 512KB
    float* alE2 = xr2 + BB * NN * D;                            // 32KB

    k_mask_gemm<<<256 + BB * NN / 4, 256, 0, stream>>>(emb, mask, x, Wl1, Wr1, att1, xl, xr, alE);

    // attn layer 1 (relu) + fused layer-2 dual GEMM (row-local dependency)
    k_attn<true, true><<<BB * NN / 4, 256, 0, stream>>>(
        xl, xr, att1, alE, b1, mask, xl2 /*unused out*/,
        Wl2, Wr2, att2, xl2, xr2, alE2);

    // attn layer 2 -> final output
    k_attn<false, false><<<BB * NN / 4, 256, 0, stream>>>(
        xl2, xr2, att2, alE2, b2, mask, out,
        Wl2, Wr2, att2, xl2, xr2, alE2 /*unused*/);
}